// Round 3
// baseline (352.191 us; speedup 1.0000x reference)
//
#include <hip/hip_runtime.h>
#include <math.h>

// nanoGPT Head: x[B,T,C] @ W{q,k,v}[C,H] -> causal softmax(QK^T/sqrt(H)) V
#define BB 8
#define TT 4096
#define CC 64
#define HH 128
#define BQ 64          // Q rows per block (4 waves x 16)
#define BK 64          // keys per tile
#define NTH 256
#define KSTR 136       // K-tile LDS row stride in bf16 (128 + 8)
#define VSTR 72        // Vt-tile LDS row stride in bf16 (64 + 8)
#define PSTR 72        // P LDS row stride in bf16
#define XSTR 72        // proj x / vstage stride
#define WSTR 72        // proj W-tile stride
// 128^-0.5 * log2(e): folded into Wq so S-scores are in log2 domain
#define QSCALE ((float)(0.08838834764831845 * 1.4426950408889634))

typedef __attribute__((ext_vector_type(8))) short short8;   // 8 bf16 (MFMA A/B frag)
typedef __attribute__((ext_vector_type(4))) float floatx4;  // MFMA C/D frag

__device__ __forceinline__ unsigned short f2bf(float f) {
    union { float f; unsigned int u; } un; un.f = f;
    unsigned int r = un.u + 0x7FFF + ((un.u >> 16) & 1);   // RNE
    return (unsigned short)(r >> 16);
}

// ---------------- Kernel 0: W -> bf16, transposed [mat][h][c]; Wq pre-scaled ----------------
__global__ __launch_bounds__(256) void wtrans(
    const float* __restrict__ Wq, const float* __restrict__ Wk, const float* __restrict__ Wv,
    unsigned short* __restrict__ Wt)
{
    const float* W = blockIdx.x == 0 ? Wq : (blockIdx.x == 1 ? Wk : Wv);
    const float s = blockIdx.x == 0 ? QSCALE : 1.0f;
    unsigned short* o = Wt + blockIdx.x * HH * CC;
    for (int idx = threadIdx.x; idx < CC * HH; idx += 256) {
        const int c = idx >> 7, h = idx & 127;
        o[h * CC + c] = f2bf(W[idx] * s);
    }
}

// ---------------- Kernel 1: QKV projection via MFMA ----------------
// Block = 64 t-rows, 256 threads (4 waves x 16 rows). q,k written [B,T,H];
// v transposed through LDS and written [B,H,T] in contiguous 64B runs.
__global__ __launch_bounds__(NTH) void qkv_mfma(
    const float* __restrict__ x, const unsigned short* __restrict__ Wt,
    unsigned short* __restrict__ qb, unsigned short* __restrict__ kb,
    unsigned short* __restrict__ vtb)
{
    __shared__ __align__(16) unsigned short xs[64 * XSTR];   // x tile bf16
    __shared__ __align__(16) unsigned short Ws[HH * WSTR];   // one W tile at a time
    __shared__ __align__(16) unsigned short vst[HH * XSTR];  // v staged [h][t]

    const int tid  = threadIdx.x;
    const int w    = tid >> 6;
    const int lane = tid & 63;
    const int quad = lane >> 4;
    const int lr   = lane & 15;

    const int b  = blockIdx.x >> 6;
    const int t0 = (blockIdx.x & 63) * 64;
    const long long rbase = (long long)b * TT + t0;

    // stage x tile (64 x 64 fp32 -> bf16)
#pragma unroll
    for (int i = 0; i < 4; ++i) {
        const int idx = tid + i * NTH;
        const int r = idx >> 4, c4 = idx & 15;
        const float4 v = *(const float4*)(x + (rbase + r) * CC + c4 * 4);
        unsigned short tmp[4] = { f2bf(v.x), f2bf(v.y), f2bf(v.z), f2bf(v.w) };
        *(unsigned long long*)&xs[r * XSTR + c4 * 4] = *(unsigned long long*)tmp;
    }
    __syncthreads();

    // A-fragments: row = w*16 + lr, k = f*32 + quad*8 + j
    short8 ax[2];
#pragma unroll
    for (int f = 0; f < 2; ++f)
        ax[f] = *(const short8*)&xs[(w * 16 + lr) * XSTR + f * 32 + quad * 8];

    for (int mat = 0; mat < 3; ++mat) {
        __syncthreads();   // prior mat's Ws reads done
#pragma unroll
        for (int i = 0; i < 4; ++i) {
            const int idx = tid + i * NTH;
            const int h = idx >> 3, c = idx & 7;
            *(float4*)&Ws[h * WSTR + c * 8] = ((const float4*)(Wt + mat * HH * CC))[idx];
        }
        __syncthreads();

#pragma unroll
        for (int nt = 0; nt < 8; ++nt) {
            floatx4 acc = (floatx4)0.f;
            const short8 b0 = *(const short8*)&Ws[(nt * 16 + lr) * WSTR + quad * 8];
            const short8 b1 = *(const short8*)&Ws[(nt * 16 + lr) * WSTR + 32 + quad * 8];
            acc = __builtin_amdgcn_mfma_f32_16x16x32_bf16(ax[0], b0, acc, 0, 0, 0);
            acc = __builtin_amdgcn_mfma_f32_16x16x32_bf16(ax[1], b1, acc, 0, 0, 0);
            // C/D: col = lr (h-sub), row = quad*4 + r (t-sub)
            if (mat == 0) {
#pragma unroll
                for (int r = 0; r < 4; ++r)
                    qb[(rbase + w * 16 + quad * 4 + r) * HH + nt * 16 + lr] = f2bf(acc[r]);
            } else if (mat == 1) {
#pragma unroll
                for (int r = 0; r < 4; ++r)
                    kb[(rbase + w * 16 + quad * 4 + r) * HH + nt * 16 + lr] = f2bf(acc[r]);
            } else {
#pragma unroll
                for (int r = 0; r < 4; ++r)
                    vst[(nt * 16 + lr) * XSTR + w * 16 + quad * 4 + r] = f2bf(acc[r]);
            }
        }
    }
    __syncthreads();

    // vst[h][t] -> vtb[b][h][t0..t0+63], coalesced
    const int h = tid >> 1, half = tid & 1;
#pragma unroll
    for (int j = 0; j < 4; ++j) {
        const float4 d = *(const float4*)&vst[h * XSTR + half * 32 + j * 8];
        *(float4*)(vtb + ((long long)b * HH + h) * TT + t0 + half * 32 + j * 8) = d;
    }
}

// ---------------- Kernel 2: bf16 MFMA flash attention ----------------
// mfma_f32_16x16x32_bf16: A: m=lane&15, k=quad*8+j; B: n=lane&15, k=quad*8+j;
// C/D: col=lane&15, row=quad*4+reg.
__global__ __launch_bounds__(NTH) void flash_mfma(
    const unsigned short* __restrict__ qb,
    const unsigned short* __restrict__ kb,
    const unsigned short* __restrict__ vtb,
    float* __restrict__ out)
{
    __shared__ __align__(16) unsigned short Ks[BK * KSTR];
    __shared__ __align__(16) unsigned short Vts[HH * VSTR];
    __shared__ __align__(16) unsigned short Ps[4 * 16 * PSTR];

    const int tid  = threadIdx.x;
    const int w    = tid >> 6;
    const int lane = tid & 63;
    const int quad = lane >> 4;
    const int lr   = lane & 15;

    const int b  = blockIdx.x & (BB - 1);
    const int qt = (TT / BQ) - 1 - (blockIdx.x >> 3);   // heavy blocks first
    const int q0 = qt * BQ;
    const long long baset = (long long)b * TT;

    // Q fragments (scale*log2e already folded in via Wq)
    short8 aq[4];
    {
        const unsigned short* qrp = qb + (baset + q0 + w * 16 + lr) * HH + quad * 8;
#pragma unroll
        for (int f = 0; f < 4; ++f)
            aq[f] = *(const short8*)(qrp + f * 32);
    }

    floatx4 o_acc[8];
#pragma unroll
    for (int dt = 0; dt < 8; ++dt) o_acc[dt] = (floatx4)0.f;
    float m_i[4] = {-INFINITY, -INFINITY, -INFINITY, -INFINITY};
    float l_i[4] = {0.f, 0.f, 0.f, 0.f};     // per-lane partials; reduced at end

    unsigned short* Pw = Ps + w * 16 * PSTR;

    // register double-buffer of K/V tiles
    float4 kreg[4], vreg[4];
    {
        const int k0 = 0;
#pragma unroll
        for (int i = 0; i < 4; ++i) {
            const int idx = tid + i * NTH;
            kreg[i] = *(const float4*)(kb + (baset + k0 + (idx >> 4)) * HH + (idx & 15) * 8);
        }
#pragma unroll
        for (int i = 0; i < 4; ++i) {
            const int idx = tid + i * NTH;
            vreg[i] = *(const float4*)(vtb + ((long long)b * HH + (idx >> 3)) * TT + k0 + (idx & 7) * 8);
        }
    }

    for (int kt = 0; kt <= qt; ++kt) {
        __syncthreads();   // A: prior-iter LDS readers done; drains exactly the loads we consume next
#pragma unroll
        for (int i = 0; i < 4; ++i) {
            const int idx = tid + i * NTH;
            *(float4*)&Ks[(idx >> 4) * KSTR + (idx & 15) * 8] = kreg[i];
        }
#pragma unroll
        for (int i = 0; i < 4; ++i) {
            const int idx = tid + i * NTH;
            *(float4*)&Vts[(idx >> 3) * VSTR + (idx & 7) * 8] = vreg[i];
        }
        __syncthreads();   // B

        if (kt < qt) {     // prefetch next tile; latency hidden behind S/softmax/PV
            const int k0n = (kt + 1) * BK;
#pragma unroll
            for (int i = 0; i < 4; ++i) {
                const int idx = tid + i * NTH;
                kreg[i] = *(const float4*)(kb + (baset + k0n + (idx >> 4)) * HH + (idx & 15) * 8);
            }
#pragma unroll
            for (int i = 0; i < 4; ++i) {
                const int idx = tid + i * NTH;
                vreg[i] = *(const float4*)(vtb + ((long long)b * HH + (idx >> 3)) * TT + k0n + (idx & 7) * 8);
            }
        }

        // ---- S = Q K^T (log2 domain) ----
        floatx4 s_acc[4];
#pragma unroll
        for (int t = 0; t < 4; ++t) s_acc[t] = (floatx4)0.f;
#pragma unroll
        for (int f = 0; f < 4; ++f)
#pragma unroll
            for (int t = 0; t < 4; ++t) {
                const short8 bk = *(const short8*)&Ks[(t * 16 + lr) * KSTR + f * 32 + quad * 8];
                s_acc[t] = __builtin_amdgcn_mfma_f32_16x16x32_bf16(aq[f], bk, s_acc[t], 0, 0, 0);
            }

        const bool diag = (kt == qt);
        float alpha[4];
#pragma unroll
        for (int r = 0; r < 4; ++r) {
            float sv[4];
#pragma unroll
            for (int t = 0; t < 4; ++t) sv[t] = s_acc[t][r];
            if (diag) {
                const int qr = q0 + w * 16 + quad * 4 + r;
#pragma unroll
                for (int t = 0; t < 4; ++t)
                    if (qt * BK + t * 16 + lr > qr) sv[t] = -INFINITY;
            }
            float rmax = fmaxf(fmaxf(sv[0], sv[1]), fmaxf(sv[2], sv[3]));
#pragma unroll
            for (int msk = 1; msk < 16; msk <<= 1)
                rmax = fmaxf(rmax, __shfl_xor(rmax, msk));
            const float mnew = fmaxf(m_i[r], rmax);
            alpha[r] = exp2f(m_i[r] - mnew);
            float lsum = 0.f;
#pragma unroll
            for (int t = 0; t < 4; ++t) {
                const float p = exp2f(sv[t] - mnew);
                lsum += p;
                Pw[(quad * 4 + r) * PSTR + t * 16 + lr] = f2bf(p);
            }
            l_i[r] = l_i[r] * alpha[r] + lsum;   // per-lane partial, no shuffle
            m_i[r] = mnew;
        }
#pragma unroll
        for (int dt = 0; dt < 8; ++dt) {
            o_acc[dt][0] *= alpha[0]; o_acc[dt][1] *= alpha[1];
            o_acc[dt][2] *= alpha[2]; o_acc[dt][3] *= alpha[3];
        }
        __syncthreads();   // C: P visible

        // ---- O += P V ----
        const short8 ap0 = *(const short8*)&Pw[lr * PSTR + quad * 8];
        const short8 ap1 = *(const short8*)&Pw[lr * PSTR + 32 + quad * 8];
#pragma unroll
        for (int dt = 0; dt < 8; ++dt) {
            const short8 bv0 = *(const short8*)&Vts[(dt * 16 + lr) * VSTR + quad * 8];
            const short8 bv1 = *(const short8*)&Vts[(dt * 16 + lr) * VSTR + 32 + quad * 8];
            o_acc[dt] = __builtin_amdgcn_mfma_f32_16x16x32_bf16(ap0, bv0, o_acc[dt], 0, 0, 0);
            o_acc[dt] = __builtin_amdgcn_mfma_f32_16x16x32_bf16(ap1, bv1, o_acc[dt], 0, 0, 0);
        }
    }

    // final 16-lane reduction of l, then epilogue
    float inv[4];
#pragma unroll
    for (int r = 0; r < 4; ++r) {
        float s = l_i[r];
#pragma unroll
        for (int msk = 1; msk < 16; msk <<= 1)
            s += __shfl_xor(s, msk);
        inv[r] = 1.f / s;
    }
#pragma unroll
    for (int r = 0; r < 4; ++r) {
        float* op = out + (baset + q0 + w * 16 + quad * 4 + r) * HH;
#pragma unroll
        for (int dt = 0; dt < 8; ++dt)
            op[dt * 16 + lr] = o_acc[dt][r] * inv[r];
    }
}

extern "C" void kernel_launch(void* const* d_in, const int* in_sizes, int n_in,
                              void* d_out, int out_size, void* d_ws, size_t ws_size,
                              hipStream_t stream)
{
    const float* x  = (const float*)d_in[0];
    const float* Wq = (const float*)d_in[1];
    const float* Wk = (const float*)d_in[2];
    const float* Wv = (const float*)d_in[3];
    float* out = (float*)d_out;

    const long long n = (long long)BB * TT * HH;   // 4,194,304
    unsigned short* qb  = (unsigned short*)d_ws;
    unsigned short* kb  = qb + n;
    unsigned short* vtb = kb + n;
    unsigned short* Wt  = vtb + n;                 // 3*128*64 bf16

    wtrans<<<3, 256, 0, stream>>>(Wq, Wk, Wv, Wt);
    qkv_mfma<<<BB * (TT / 64), NTH, 0, stream>>>(x, Wt, qb, kb, vtb);
    flash_mfma<<<BB * (TT / BQ), NTH, 0, stream>>>(qb, kb, vtb, out);
}

// Round 4
// 227.124 us; speedup vs baseline: 1.5507x; 1.5507x over previous
//
#include <hip/hip_runtime.h>
#include <math.h>

// nanoGPT Head: x[B,T,C] @ W{q,k,v}[C,H] -> causal softmax(QK^T/sqrt(H)) V
#define BB 8
#define TT 4096
#define CC 64
#define HH 128
#define BQ 64          // Q rows per block (4 waves x 16)
#define BK 64          // keys per tile
#define NTH 256
#define PSTR 72        // P LDS row stride in bf16 (64+8)
#define XSTR 72        // proj x stride
#define WSTR 72        // proj W stride
// 128^-0.5 * log2(e): folded into Wq so S-scores are in log2 domain
#define QSCALE ((float)(0.08838834764831845 * 1.4426950408889634))

typedef __attribute__((ext_vector_type(8))) short short8;   // 8 bf16 (MFMA A/B frag)
typedef __attribute__((ext_vector_type(4))) float floatx4;  // MFMA C/D frag

__device__ __forceinline__ unsigned short f2bf(float f) {
    union { float f; unsigned int u; } un; un.f = f;
    unsigned int r = un.u + 0x7FFF + ((un.u >> 16) & 1);   // RNE
    return (unsigned short)(r >> 16);
}

// async global->LDS, 16B per lane; lds dest = wave-uniform base + lane*16
__device__ __forceinline__ void gl_lds16(const void* g, void* l) {
    __builtin_amdgcn_global_load_lds(
        (const __attribute__((address_space(1))) unsigned int*)g,
        (__attribute__((address_space(3))) unsigned int*)l, 16, 0, 0);
}

// ---------------- Kernel 0: W -> bf16, transposed [mat][h][c]; Wq pre-scaled ----------------
__global__ __launch_bounds__(256) void wtrans(
    const float* __restrict__ Wq, const float* __restrict__ Wk, const float* __restrict__ Wv,
    unsigned short* __restrict__ Wt)
{
    const int mat = blockIdx.x >> 3, blk = blockIdx.x & 7;
    const float* W = mat == 0 ? Wq : (mat == 1 ? Wk : Wv);
    const float s = mat == 0 ? QSCALE : 1.0f;
    unsigned short* o = Wt + mat * HH * CC;
#pragma unroll
    for (int i = 0; i < 4; ++i) {
        const int idx = blk * 1024 + threadIdx.x + i * 256;   // [0, 8192)
        const int c = idx >> 7, h = idx & 127;
        o[h * CC + c] = f2bf(W[idx] * s);
    }
}

// ---------------- Kernel 1: QKV projection via MFMA, packed stores ----------------
// Block = 64 t-rows, 256 threads (4 waves x 16 t's each).
// Q,K computed as C^T = W·X^T (A=W-frag, B=x-frag) -> lane holds 4 consecutive h -> ushort4 store to [B,T,H].
// V computed as C = X·W  (A=x-frag, B=W-frag) -> lane holds 4 consecutive t -> ushort4 store to [B,H,T].
__global__ __launch_bounds__(NTH) void qkv_mfma(
    const float* __restrict__ x, const unsigned short* __restrict__ Wt,
    unsigned short* __restrict__ qb, unsigned short* __restrict__ kb,
    unsigned short* __restrict__ vtb)
{
    __shared__ __align__(16) unsigned short xs[64 * XSTR];        // x tile bf16
    __shared__ __align__(16) unsigned short Wts[3 * HH * WSTR];   // all three W^T tiles

    const int tid  = threadIdx.x;
    const int w    = tid >> 6;
    const int lane = tid & 63;
    const int quad = lane >> 4;
    const int lr   = lane & 15;

    const int b  = blockIdx.x >> 6;
    const int t0 = (blockIdx.x & 63) * 64;
    const long long rbase = (long long)b * TT + t0;

    // stage x tile (64 x 64 fp32 -> bf16)
#pragma unroll
    for (int i = 0; i < 4; ++i) {
        const int idx = tid + i * NTH;
        const int r = idx >> 4, c4 = idx & 15;
        const float4 v = *(const float4*)(x + (rbase + r) * CC + c4 * 4);
        unsigned short tmp[4] = { f2bf(v.x), f2bf(v.y), f2bf(v.z), f2bf(v.w) };
        *(unsigned long long*)&xs[r * XSTR + c4 * 4] = *(unsigned long long*)tmp;
    }
    // stage all W^T: 3*128 rows x 64 cols = 3072 float4
#pragma unroll
    for (int i = 0; i < 12; ++i) {
        const int idx = tid + i * NTH;
        const int row = idx >> 3, c8 = idx & 7;
        *(float4*)&Wts[row * WSTR + c8 * 8] = ((const float4*)Wt)[idx];
    }
    __syncthreads();

    // x fragments (serve as both A and B operand: lane&15 -> t-local, quad*8+j -> c)
    const short8 bx0 = *(const short8*)&xs[(w * 16 + lr) * XSTR + quad * 8];
    const short8 bx1 = *(const short8*)&xs[(w * 16 + lr) * XSTR + 32 + quad * 8];

    // Q and K: C^T[h][t]
#pragma unroll
    for (int mat = 0; mat < 2; ++mat) {
        unsigned short* dst = mat ? kb : qb;
        const unsigned short* Wrow = Wts + mat * HH * WSTR;
#pragma unroll
        for (int ht = 0; ht < 8; ++ht) {
            const short8 aw0 = *(const short8*)(Wrow + (ht * 16 + lr) * WSTR + quad * 8);
            const short8 aw1 = *(const short8*)(Wrow + (ht * 16 + lr) * WSTR + 32 + quad * 8);
            floatx4 acc = (floatx4)0.f;
            acc = __builtin_amdgcn_mfma_f32_16x16x32_bf16(aw0, bx0, acc, 0, 0, 0);
            acc = __builtin_amdgcn_mfma_f32_16x16x32_bf16(aw1, bx1, acc, 0, 0, 0);
            // C/D: col=lr -> t-local, row=quad*4+r -> h-local (4 consecutive h)
            ushort4 st = { f2bf(acc[0]), f2bf(acc[1]), f2bf(acc[2]), f2bf(acc[3]) };
            *(ushort4*)(dst + (rbase + w * 16 + lr) * HH + ht * 16 + quad * 4) = st;
        }
    }
    // V: C[t][h] -> vt[b][h][t] with 4 consecutive t per lane
    {
        const unsigned short* Wrow = Wts + 2 * HH * WSTR;
#pragma unroll
        for (int ht = 0; ht < 8; ++ht) {
            const short8 bw0 = *(const short8*)(Wrow + (ht * 16 + lr) * WSTR + quad * 8);
            const short8 bw1 = *(const short8*)(Wrow + (ht * 16 + lr) * WSTR + 32 + quad * 8);
            floatx4 acc = (floatx4)0.f;
            acc = __builtin_amdgcn_mfma_f32_16x16x32_bf16(bx0, bw0, acc, 0, 0, 0);
            acc = __builtin_amdgcn_mfma_f32_16x16x32_bf16(bx1, bw1, acc, 0, 0, 0);
            // C/D: col=lr -> h-local, row=quad*4+r -> t-local (4 consecutive t)
            ushort4 st = { f2bf(acc[0]), f2bf(acc[1]), f2bf(acc[2]), f2bf(acc[3]) };
            *(ushort4*)(vtb + ((long long)b * HH + ht * 16 + lr) * TT + t0 + w * 16 + quad * 4) = st;
        }
    }
}

// ---------------- Kernel 2: bf16 MFMA flash attention, async LDS dbuf ----------------
// K buffer: 64 rows x 16 chunks(16B); slot(row,c) = row*16 + (c&8)|((c^row)&7)
// V buffer: 128 rows x 8 chunks(16B); slot(row,c) = row*8  + (c^row)&7
__device__ __forceinline__ void prefetch_kv(
    const unsigned short* __restrict__ kb_t,   // kb + (baset+k0)*HH
    const unsigned short* __restrict__ vt_t,   // vtb + b*HH*TT + k0
    unsigned char* Kd, unsigned char* Vd, int w, int lane)
{
#pragma unroll
    for (int c = 0; c < 4; ++c) {
        const int slot = w * 256 + c * 64 + lane;
        const int row = slot >> 4, cp = slot & 15;
        const int col = (cp & 8) | ((cp ^ row) & 7);
        gl_lds16(kb_t + row * HH + col * 8, Kd + (w * 256 + c * 64) * 16);
    }
#pragma unroll
    for (int c = 0; c < 4; ++c) {
        const int slot = w * 256 + c * 64 + lane;
        const int row = slot >> 3, cp = slot & 7;
        const int col = (cp ^ row) & 7;
        gl_lds16(vt_t + (long long)row * TT + col * 8, Vd + (w * 256 + c * 64) * 16);
    }
}

__global__ __launch_bounds__(NTH) void flash_mfma(
    const unsigned short* __restrict__ qb,
    const unsigned short* __restrict__ kb,
    const unsigned short* __restrict__ vtb,
    float* __restrict__ out)
{
    __shared__ __align__(16) unsigned char Kbuf[2][16384];
    __shared__ __align__(16) unsigned char Vbuf[2][16384];
    __shared__ __align__(16) unsigned short Ps[4 * 16 * PSTR];

    const int tid  = threadIdx.x;
    const int w    = tid >> 6;
    const int lane = tid & 63;
    const int quad = lane >> 4;
    const int lr   = lane & 15;

    const int b = blockIdx.x & (BB - 1);
    const int j = blockIdx.x >> 3;
    const int qt = (j & 1) ? (j >> 1) : (63 - (j >> 1));   // interleave heavy/light
    const int q0 = qt * BQ;
    const long long baset = (long long)b * TT;
    const unsigned short* kb_b = kb + baset * HH;
    const unsigned short* vt_b = vtb + (long long)b * HH * TT;

    // prologue: prefetch tile 0 into buf0
    prefetch_kv(kb_b, vt_b, Kbuf[0], Vbuf[0], w, lane);

    // Q fragments (scale*log2e folded in via Wq)
    short8 aq[4];
    {
        const unsigned short* qrp = qb + (baset + q0 + w * 16 + lr) * HH + quad * 8;
#pragma unroll
        for (int f = 0; f < 4; ++f)
            aq[f] = *(const short8*)(qrp + f * 32);
    }

    floatx4 o_acc[8];                       // O^T: lane holds h = dt*16+quad*4+r, t-local = lr
#pragma unroll
    for (int dt = 0; dt < 8; ++dt) o_acc[dt] = (floatx4)0.f;
    float m_i[4] = {-INFINITY, -INFINITY, -INFINITY, -INFINITY};
    float l_i[4] = {0.f, 0.f, 0.f, 0.f};    // per-lane partials (rows quad*4+r)

    unsigned short* Pw = Ps + w * 16 * PSTR;
    const int bcast = (((lane & 15) >> 2) << 4) | (lane & 15);   // src lane holding row lr's stats

    for (int kt = 0; kt <= qt; ++kt) {
        __syncthreads();   // vmcnt(0) drain: buf[kt&1] DMA complete; prev-iter LDS readers done
        const unsigned short* Kt = (const unsigned short*)Kbuf[kt & 1];
        const unsigned short* Vt = (const unsigned short*)Vbuf[kt & 1];

        // ---- S = Q K^T (log2 domain): C row=query(quad*4+r), col=key(t*16+lr) ----
        floatx4 s_acc[4];
#pragma unroll
        for (int t = 0; t < 4; ++t) s_acc[t] = (floatx4)0.f;
#pragma unroll
        for (int f = 0; f < 4; ++f)
#pragma unroll
            for (int t = 0; t < 4; ++t) {
                const int cc = f * 4 + quad;
                const int chunk = ((t * 16 + lr) << 4) | (cc & 8) | ((cc ^ lr) & 7);
                const short8 bk = *(const short8*)(Kt + chunk * 8);
                s_acc[t] = __builtin_amdgcn_mfma_f32_16x16x32_bf16(aq[f], bk, s_acc[t], 0, 0, 0);
            }

        // ---- online softmax, write P ----
        const bool diag = (kt == qt);
        float alpha[4];
#pragma unroll
        for (int r = 0; r < 4; ++r) {
            float sv[4];
#pragma unroll
            for (int t = 0; t < 4; ++t) sv[t] = s_acc[t][r];
            if (diag) {
                const int qr = q0 + w * 16 + quad * 4 + r;
#pragma unroll
                for (int t = 0; t < 4; ++t)
                    if (qt * BK + t * 16 + lr > qr) sv[t] = -INFINITY;
            }
            float rmax = fmaxf(fmaxf(sv[0], sv[1]), fmaxf(sv[2], sv[3]));
#pragma unroll
            for (int msk = 1; msk < 16; msk <<= 1)
                rmax = fmaxf(rmax, __shfl_xor(rmax, msk));
            const float mnew = fmaxf(m_i[r], rmax);
            alpha[r] = exp2f(m_i[r] - mnew);
            float lsum = 0.f;
#pragma unroll
            for (int t = 0; t < 4; ++t) {
                const float p = exp2f(sv[t] - mnew);
                lsum += p;
                Pw[(quad * 4 + r) * PSTR + t * 16 + lr] = f2bf(p);
            }
            l_i[r] = l_i[r] * alpha[r] + lsum;
            m_i[r] = mnew;
        }
        // broadcast alpha to O^T layout (factor for query row lr)
        const float asel = (lane & 2) ? ((lane & 1) ? alpha[3] : alpha[2])
                                      : ((lane & 1) ? alpha[1] : alpha[0]);
        const float alphaL = __shfl(asel, bcast);
#pragma unroll
        for (int dt = 0; dt < 8; ++dt) {
            o_acc[dt][0] *= alphaL; o_acc[dt][1] *= alphaL;
            o_acc[dt][2] *= alphaL; o_acc[dt][3] *= alphaL;
        }
        __syncthreads();   // P visible (nothing in flight: no vmem issued since loop top)

        // prefetch next tile into the other buffer; in flight across PV + next S/softmax
        if (kt < qt) {
            const int k0n = (kt + 1) * BK;
            prefetch_kv(kb_b + (long long)k0n * HH, vt_b + k0n,
                        Kbuf[(kt + 1) & 1], Vbuf[(kt + 1) & 1], w, lane);
        }

        // ---- O^T += (P V)^T = Vt · P^T : A = Vt-frag, B = P-frag ----
        const short8 bp0 = *(const short8*)&Pw[lr * PSTR + quad * 8];
        const short8 bp1 = *(const short8*)&Pw[lr * PSTR + 32 + quad * 8];
#pragma unroll
        for (int dt = 0; dt < 8; ++dt) {
            const int rr = dt * 16 + lr;
            const int ch0 = (rr << 3) | ((quad ^ lr) & 7);
            const int ch1 = (rr << 3) | (((4 + quad) ^ lr) & 7);
            const short8 av0 = *(const short8*)(Vt + ch0 * 8);
            const short8 av1 = *(const short8*)(Vt + ch1 * 8);
            o_acc[dt] = __builtin_amdgcn_mfma_f32_16x16x32_bf16(av0, bp0, o_acc[dt], 0, 0, 0);
            o_acc[dt] = __builtin_amdgcn_mfma_f32_16x16x32_bf16(av1, bp1, o_acc[dt], 0, 0, 0);
        }
    }

    // ---- epilogue: row sums of l, broadcast inverse, packed float4 stores ----
    float inv[4];
#pragma unroll
    for (int r = 0; r < 4; ++r) {
        float s = l_i[r];
#pragma unroll
        for (int msk = 1; msk < 16; msk <<= 1)
            s += __shfl_xor(s, msk);
        inv[r] = 1.f / s;
    }
    const float isel = (lane & 2) ? ((lane & 1) ? inv[3] : inv[2])
                                  : ((lane & 1) ? inv[1] : inv[0]);
    const float invL = __shfl(isel, bcast);

    float* op = out + (baset + q0 + w * 16 + lr) * HH;
#pragma unroll
    for (int dt = 0; dt < 8; ++dt) {
        float4 st = make_float4(o_acc[dt][0] * invL, o_acc[dt][1] * invL,
                                o_acc[dt][2] * invL, o_acc[dt][3] * invL);
        *(float4*)(op + dt * 16 + quad * 4) = st;
    }
}

extern "C" void kernel_launch(void* const* d_in, const int* in_sizes, int n_in,
                              void* d_out, int out_size, void* d_ws, size_t ws_size,
                              hipStream_t stream)
{
    const float* x  = (const float*)d_in[0];
    const float* Wq = (const float*)d_in[1];
    const float* Wk = (const float*)d_in[2];
    const float* Wv = (const float*)d_in[3];
    float* out = (float*)d_out;

    const long long n = (long long)BB * TT * HH;   // 4,194,304
    unsigned short* qb  = (unsigned short*)d_ws;
    unsigned short* kb  = qb + n;
    unsigned short* vtb = kb + n;
    unsigned short* Wt  = vtb + n;                 // 3*128*64 bf16

    wtrans<<<24, 256, 0, stream>>>(Wq, Wk, Wv, Wt);
    qkv_mfma<<<BB * (TT / 64), NTH, 0, stream>>>(x, Wt, qb, kb, vtb);
    flash_mfma<<<BB * (TT / BQ), NTH, 0, stream>>>(qb, kb, vtb, out);
}

// Round 5
// 183.524 us; speedup vs baseline: 1.9190x; 1.2376x over previous
//
#include <hip/hip_runtime.h>
#include <math.h>

// nanoGPT Head: x[B,T,C] @ W{q,k,v}[C,H] -> causal softmax(QK^T/sqrt(H)) V
#define BB 8
#define TT 4096
#define CC 64
#define HH 128
#define BQ 64          // Q rows per flash block
#define BK 64          // keys per tile
#define NTH 256
#define PST 40         // P LDS row stride in bf16 (32+8; 80B keeps b128 16B-aligned)
#define XSTR 72        // proj x stride (144B = 16*9, b128-aligned)
#define WSTR 72        // proj W stride
// 128^-0.5 * log2(e): folded into Wq so S-scores are in log2 domain
#define QSCALE ((float)(0.08838834764831845 * 1.4426950408889634))

typedef __attribute__((ext_vector_type(8)))  short short8;    // 8 bf16 (MFMA A/B frag)
typedef __attribute__((ext_vector_type(4)))  float floatx4;   // 16x16 C/D frag
typedef __attribute__((ext_vector_type(16))) float floatx16;  // 32x32 C/D frag

__device__ __forceinline__ unsigned short f2bf(float f) {
    union { float f; unsigned int u; } un; un.f = f;
    unsigned int r = un.u + 0x7FFF + ((un.u >> 16) & 1);   // RNE
    return (unsigned short)(r >> 16);
}

// async global->LDS, 16B per lane; lds dest = wave-uniform base + lane*16
__device__ __forceinline__ void gl_lds16(const void* g, void* l) {
    __builtin_amdgcn_global_load_lds(
        (const __attribute__((address_space(1))) unsigned int*)g,
        (__attribute__((address_space(3))) unsigned int*)l, 16, 0, 0);
}

// ---------------- Kernel 1: QKV projection via MFMA (wtrans fused) ----------------
// Block = 64 t-rows, 256 threads. Q,K as C^T (lane holds 4 consecutive h) -> ushort4 to [B,T,H].
// V as C (lane holds 4 consecutive t) -> ushort4 to [B,H,T].
__global__ __launch_bounds__(NTH) void qkv_mfma(
    const float* __restrict__ x,
    const float* __restrict__ Wq, const float* __restrict__ Wk, const float* __restrict__ Wv,
    unsigned short* __restrict__ qb, unsigned short* __restrict__ kb,
    unsigned short* __restrict__ vtb)
{
    __shared__ __align__(16) unsigned short xs[64 * XSTR];        // x tile bf16
    __shared__ __align__(16) unsigned short Wts[3 * HH * WSTR];   // W^T bf16, [mat][h][c]

    const int tid  = threadIdx.x;
    const int w    = tid >> 6;
    const int lane = tid & 63;
    const int quad = lane >> 4;
    const int lr   = lane & 15;

    const int b  = blockIdx.x >> 6;
    const int t0 = (blockIdx.x & 63) * 64;
    const long long rbase = (long long)b * TT + t0;

    // stage x tile (64 x 64 fp32 -> bf16)
#pragma unroll
    for (int i = 0; i < 4; ++i) {
        const int idx = tid + i * NTH;
        const int r = idx >> 4, c4 = idx & 15;
        const float4 v = *(const float4*)(x + (rbase + r) * CC + c4 * 4);
        unsigned short tmp[4] = { f2bf(v.x), f2bf(v.y), f2bf(v.z), f2bf(v.w) };
        *(unsigned long long*)&xs[r * XSTR + c4 * 4] = *(unsigned long long*)tmp;
    }
    // fused wtrans: W[c][h] fp32 -> Wts[mat][h][c] bf16 (Wq pre-scaled; L2-hot after block 0)
#pragma unroll
    for (int mat = 0; mat < 3; ++mat) {
        const float* W = mat == 0 ? Wq : (mat == 1 ? Wk : Wv);
        const float s = mat == 0 ? QSCALE : 1.0f;
#pragma unroll
        for (int i = 0; i < 32; ++i) {
            const int idx = tid + i * NTH;            // [0, 8192)
            const int c = idx >> 7, h = idx & 127;
            Wts[(mat * HH + h) * WSTR + c] = f2bf(W[idx] * s);
        }
    }
    __syncthreads();

    // x fragments (A or B operand: lane&15 -> t-local, quad*8+j -> c)
    const short8 bx0 = *(const short8*)&xs[(w * 16 + lr) * XSTR + quad * 8];
    const short8 bx1 = *(const short8*)&xs[(w * 16 + lr) * XSTR + 32 + quad * 8];

    // Q and K: C^T[h][t]
#pragma unroll
    for (int mat = 0; mat < 2; ++mat) {
        unsigned short* dst = mat ? kb : qb;
        const unsigned short* Wrow = Wts + mat * HH * WSTR;
#pragma unroll
        for (int ht = 0; ht < 8; ++ht) {
            const short8 aw0 = *(const short8*)(Wrow + (ht * 16 + lr) * WSTR + quad * 8);
            const short8 aw1 = *(const short8*)(Wrow + (ht * 16 + lr) * WSTR + 32 + quad * 8);
            floatx4 acc = (floatx4)0.f;
            acc = __builtin_amdgcn_mfma_f32_16x16x32_bf16(aw0, bx0, acc, 0, 0, 0);
            acc = __builtin_amdgcn_mfma_f32_16x16x32_bf16(aw1, bx1, acc, 0, 0, 0);
            ushort4 st = { f2bf(acc[0]), f2bf(acc[1]), f2bf(acc[2]), f2bf(acc[3]) };
            *(ushort4*)(dst + (rbase + w * 16 + lr) * HH + ht * 16 + quad * 4) = st;
        }
    }
    // V: C[t][h] -> vtb[b][h][t]
    {
        const unsigned short* Wrow = Wts + 2 * HH * WSTR;
#pragma unroll
        for (int ht = 0; ht < 8; ++ht) {
            const short8 bw0 = *(const short8*)(Wrow + (ht * 16 + lr) * WSTR + quad * 8);
            const short8 bw1 = *(const short8*)(Wrow + (ht * 16 + lr) * WSTR + 32 + quad * 8);
            floatx4 acc = (floatx4)0.f;
            acc = __builtin_amdgcn_mfma_f32_16x16x32_bf16(bx0, bw0, acc, 0, 0, 0);
            acc = __builtin_amdgcn_mfma_f32_16x16x32_bf16(bx1, bw1, acc, 0, 0, 0);
            ushort4 st = { f2bf(acc[0]), f2bf(acc[1]), f2bf(acc[2]), f2bf(acc[3]) };
            *(ushort4*)(vtb + ((long long)b * HH + ht * 16 + lr) * TT + t0 + w * 16 + quad * 4) = st;
        }
    }
}

// ---------------- Kernel 2: flash attention, 32x32x16 MFMA, k/q-split waves ----------------
// Wave w: kh = w&1 (key half 32), qh = w>>1 (query half 32).
// 32x32x16 layouts: A[m=lane&31][k=(lane>>5)*8+j]; B[k][n=lane&31];
// C/D: col=lane&31, row=(reg&3)+8*(reg>>2)+4*(lane>>5).
// No-max softmax: p = exp2(s) (scores pre-scaled by log2e*128^-0.5 via Wq); scale cancels in sum/div.
__device__ __forceinline__ void prefetch_kv(
    const unsigned short* __restrict__ kb_t,   // kb + (baset+k0)*HH
    const unsigned short* __restrict__ vt_t,   // vtb + b*HH*TT + k0
    unsigned char* Kd, unsigned char* Vd, int w, int lane)
{
#pragma unroll
    for (int c = 0; c < 4; ++c) {
        const int slot = w * 256 + c * 64 + lane;
        const int row = slot >> 4, cp = slot & 15;
        const int col = (cp & 8) | ((cp ^ row) & 7);
        gl_lds16(kb_t + row * HH + col * 8, Kd + (w * 256 + c * 64) * 16);
    }
#pragma unroll
    for (int c = 0; c < 4; ++c) {
        const int slot = w * 256 + c * 64 + lane;
        const int row = slot >> 3, cp = slot & 7;
        const int col = (cp ^ row) & 7;
        gl_lds16(vt_t + (long long)row * TT + col * 8, Vd + (w * 256 + c * 64) * 16);
    }
}

__global__ __launch_bounds__(NTH) void flash_mfma(
    const unsigned short* __restrict__ qb,
    const unsigned short* __restrict__ kb,
    const unsigned short* __restrict__ vtb,
    float* __restrict__ out)
{
    __shared__ __align__(16) unsigned char KV[65536];          // K dbuf [0,32K), V dbuf [32K,64K)
    __shared__ __align__(16) unsigned short Ps[4 * 32 * PST];  // per-wave P (32k x 32q region)
    __shared__ float Lx2[4][64];                               // per-wave per-lane l partials

    const int tid  = threadIdx.x;
    const int w    = tid >> 6;
    const int lane = tid & 63;
    const int lq   = lane & 31;       // query-local (n) / key-local (m) / h-local (m)
    const int ls   = lane >> 5;       // k-subgroup
    const int kh   = w & 1;           // key half of this wave
    const int qh   = w >> 1;          // query half of this wave

    // balanced CU pairing: ids i and i+256 share a CU under round-robin dispatch; qt sums to 63
    const int b = blockIdx.x & 7;
    const int s = blockIdx.x >> 3;                 // 0..63
    const int qt = (s < 32) ? (63 - s) : (s - 32);
    const int q0 = qt * BQ;
    const long long baset = (long long)b * TT;
    const unsigned short* kb_b = kb + baset * HH;
    const unsigned short* vt_b = vtb + (long long)b * HH * TT;

    unsigned char* Kb0 = KV;          // +16384*i
    unsigned char* Vb0 = KV + 32768;

    prefetch_kv(kb_b, vt_b, Kb0, Vb0, w, lane);    // tile 0 -> buf 0

    // Q fragments: rows q0 + qh*32 + lq, d = step*16 + ls*8 + j
    short8 aq[8];
    {
        const unsigned short* qrp = qb + (baset + q0 + qh * 32 + lq) * HH + ls * 8;
#pragma unroll
        for (int st = 0; st < 8; ++st)
            aq[st] = *(const short8*)(qrp + st * 16);
    }

    floatx16 o_acc[4];                // O^T partial: h = ht*32+row, q = qh*32+lq (this wave's kh keys)
#pragma unroll
    for (int ht = 0; ht < 4; ++ht) o_acc[ht] = (floatx16)0.f;
    float l_lane = 0.f;

    unsigned short* Pw = Ps + w * 32 * PST;

    for (int kt = 0; kt <= qt; ++kt) {
        __syncthreads();   // vmcnt(0) drain: buf[kt&1] DMA complete; prior-iter readers of buf[(kt+1)&1] done
        const unsigned short* Kt = (const unsigned short*)(Kb0 + (kt & 1) * 16384);
        const unsigned short* Vt = (const unsigned short*)(Vb0 + (kt & 1) * 16384);

        if (kt < qt) {     // prefetch next tile now: in flight across the whole iteration
            const int k0n = (kt + 1) * BK;
            prefetch_kv(kb_b + (long long)k0n * HH, vt_b + k0n,
                        Kb0 + ((kt + 1) & 1) * 16384, Vb0 + ((kt + 1) & 1) * 16384, w, lane);
        }

        // ---- S^T = K Q^T over this wave's 32 keys x 32 queries ----
        floatx16 s_acc = (floatx16)0.f;
#pragma unroll
        for (int st = 0; st < 8; ++st) {
            const int row = kh * 32 + lq;              // key row in tile
            const int cc = st * 2 + ls;                // 16B chunk col in 256B row
            const int chunk = (row << 4) | (cc & 8) | ((cc ^ row) & 7);
            const short8 kf = *(const short8*)(Kt + chunk * 8);
            s_acc = __builtin_amdgcn_mfma_f32_32x32x16_bf16(kf, aq[st], s_acc, 0, 0, 0);
        }

        // ---- p = exp2(s), mask on diagonal tile, accumulate l, write P ----
        const bool diag = (kt == qt);
        unsigned short ps[16];
#pragma unroll
        for (int reg = 0; reg < 16; ++reg) {
            const int rowp = (reg & 3) + 8 * (reg >> 2) + 4 * ls;   // key-local in 32
            float p = exp2f(s_acc[reg]);
            if (diag && (kh * 32 + rowp > qh * 32 + lq)) p = 0.f;
            l_lane += p;
            ps[reg] = f2bf(p);
        }
#pragma unroll
        for (int g = 0; g < 4; ++g)
            *(ushort4*)&Pw[lq * PST + 8 * g + 4 * ls] = *(ushort4*)&ps[g * 4];

        // ---- O^T += Vt · P^T (keys of this wave's half) ----
        short8 pf[2];
#pragma unroll
        for (int ks = 0; ks < 2; ++ks)
            pf[ks] = *(const short8*)&Pw[lq * PST + ks * 16 + ls * 8];
#pragma unroll
        for (int ht = 0; ht < 4; ++ht) {
#pragma unroll
            for (int ks = 0; ks < 2; ++ks) {
                const int row = ht * 32 + lq;          // h row
                const int cc2 = kh * 4 + ks * 2 + ls;  // 16B chunk col in 128B row
                const int ch = (row << 3) | ((cc2 ^ row) & 7);
                const short8 vf = *(const short8*)(Vt + ch * 8);
                o_acc[ht] = __builtin_amdgcn_mfma_f32_32x32x16_bf16(vf, pf[ks], o_acc[ht], 0, 0, 0);
            }
        }
    }

    // ---- epilogue: combine k-halves via LDS, divide by l, store ----
    Lx2[w][lane] = l_lane;
    float* ex = (float*)KV;                       // K/V buffers are dead now
    if (kh) {                                      // odd waves dump partials
        const int base = qh * 4352;                // 64 lanes * 68 floats
#pragma unroll
        for (int ht = 0; ht < 4; ++ht)
#pragma unroll
            for (int g = 0; g < 4; ++g) {
                float4 v = make_float4(o_acc[ht][g * 4 + 0], o_acc[ht][g * 4 + 1],
                                       o_acc[ht][g * 4 + 2], o_acc[ht][g * 4 + 3]);
                *(float4*)&ex[base + lane * 68 + ht * 16 + g * 4] = v;
            }
    }
    __syncthreads();
    if (!kh) {                                     // even waves combine + store
        const float linv = 1.f / (Lx2[2 * qh][lq] + Lx2[2 * qh][lq + 32] +
                                  Lx2[2 * qh + 1][lq] + Lx2[2 * qh + 1][lq + 32]);
        const int base = qh * 4352;
        float* op = out + (baset + q0 + qh * 32 + lq) * HH;
#pragma unroll
        for (int ht = 0; ht < 4; ++ht)
#pragma unroll
            for (int g = 0; g < 4; ++g) {
                const float4 pv = *(const float4*)&ex[base + lane * 68 + ht * 16 + g * 4];
                float4 stv = make_float4((o_acc[ht][g * 4 + 0] + pv.x) * linv,
                                         (o_acc[ht][g * 4 + 1] + pv.y) * linv,
                                         (o_acc[ht][g * 4 + 2] + pv.z) * linv,
                                         (o_acc[ht][g * 4 + 3] + pv.w) * linv);
                *(float4*)(op + ht * 32 + 8 * g + 4 * ls) = stv;
            }
    }
}

extern "C" void kernel_launch(void* const* d_in, const int* in_sizes, int n_in,
                              void* d_out, int out_size, void* d_ws, size_t ws_size,
                              hipStream_t stream)
{
    const float* x  = (const float*)d_in[0];
    const float* Wq = (const float*)d_in[1];
    const float* Wk = (const float*)d_in[2];
    const float* Wv = (const float*)d_in[3];
    float* out = (float*)d_out;

    const long long n = (long long)BB * TT * HH;   // 4,194,304
    unsigned short* qb  = (unsigned short*)d_ws;
    unsigned short* kb  = qb + n;
    unsigned short* vtb = kb + n;

    qkv_mfma<<<BB * (TT / 64), NTH, 0, stream>>>(x, Wq, Wk, Wv, qb, kb, vtb);
    flash_mfma<<<BB * (TT / BQ), NTH, 0, stream>>>(qb, kb, vtb, out);
}

// Round 6
// 176.443 us; speedup vs baseline: 1.9961x; 1.0401x over previous
//
#include <hip/hip_runtime.h>
#include <math.h>

// nanoGPT Head: x[B,T,C] @ W{q,k,v}[C,H] -> causal softmax(QK^T/sqrt(H)) V
#define BB 8
#define TT 4096
#define CC 64
#define HH 128
#define NTH 256
#define XSTR 72        // proj x stride (bf16)
#define WSTR 72        // proj W stride (bf16)
// 128^-0.5 * log2(e): folded into Wq so S-scores are in log2 domain
#define QSCALE ((float)(0.08838834764831845 * 1.4426950408889634))

typedef __attribute__((ext_vector_type(8)))  short short8;    // 8 bf16 (MFMA A/B frag)
typedef __attribute__((ext_vector_type(4)))  float floatx4;   // 16x16 C/D frag
typedef __attribute__((ext_vector_type(16))) float floatx16;  // 32x32 C/D frag

__device__ __forceinline__ unsigned short f2bf(float f) {
    union { float f; unsigned int u; } un; un.f = f;
    unsigned int r = un.u + 0x7FFF + ((un.u >> 16) & 1);   // RNE
    return (unsigned short)(r >> 16);
}
__device__ __forceinline__ unsigned int pack2bf(float a, float b) {
    return (unsigned int)f2bf(a) | ((unsigned int)f2bf(b) << 16);
}

// ---------------- Kernel 1: QKV projection via MFMA ----------------
// Q -> [B,T,H] row-major bf16 (flash reads per-lane rows once).
// K -> fragment-tiled: chunk(b,kt,kh,st,lane) @ ((b*64+kt)*2+kh)*4096 + st*512 + lane*8 shorts
//      content: K[t = kt*64+kh*32+(lane&31)][d = st*16+(lane>>5)*8 .. +8]
// V -> fragment-tiled: chunk(b,kt,kh,ht,ks,lane) @ (b*64+kt)*8192 + kh*4096 + ht*1024 + ks*512 + lane*8
//      content: V^T[h = ht*32+(lane&31)][key_local = kh*32+ks*16+(lane>>5)*8 .. +8]
__global__ __launch_bounds__(NTH) void qkv_mfma(
    const float* __restrict__ x,
    const float* __restrict__ Wq, const float* __restrict__ Wk, const float* __restrict__ Wv,
    unsigned short* __restrict__ qb, unsigned short* __restrict__ Kf,
    unsigned short* __restrict__ Vf)
{
    __shared__ __align__(16) unsigned short xs[64 * XSTR];        // x tile bf16
    __shared__ __align__(16) unsigned short Wts[3 * HH * WSTR];   // W^T bf16, [mat][h][c]

    const int tid  = threadIdx.x;
    const int w    = tid >> 6;
    const int lane = tid & 63;
    const int quad = lane >> 4;
    const int lr   = lane & 15;

    const int b    = blockIdx.x >> 6;
    const int kblk = blockIdx.x & 63;
    const int t0   = kblk * 64;
    const long long rbase = (long long)b * TT + t0;

    // stage x tile (64 x 64 fp32 -> bf16)
#pragma unroll
    for (int i = 0; i < 4; ++i) {
        const int idx = tid + i * NTH;
        const int r = idx >> 4, c4 = idx & 15;
        const float4 v = *(const float4*)(x + (rbase + r) * CC + c4 * 4);
        unsigned short tmp[4] = { f2bf(v.x), f2bf(v.y), f2bf(v.z), f2bf(v.w) };
        *(unsigned long long*)&xs[r * XSTR + c4 * 4] = *(unsigned long long*)tmp;
    }
    // fused wtrans: W[c][h] fp32 -> Wts[mat][h][c] bf16 (Wq pre-scaled)
#pragma unroll
    for (int mat = 0; mat < 3; ++mat) {
        const float* W = mat == 0 ? Wq : (mat == 1 ? Wk : Wv);
        const float s = mat == 0 ? QSCALE : 1.0f;
#pragma unroll
        for (int i = 0; i < 32; ++i) {
            const int idx = tid + i * NTH;            // [0, 8192)
            const int c = idx >> 7, h = idx & 127;
            Wts[(mat * HH + h) * WSTR + c] = f2bf(W[idx] * s);
        }
    }
    __syncthreads();

    // x fragments (A or B operand: lane&15 -> t-local, quad*8+j -> c)
    const short8 bx0 = *(const short8*)&xs[(w * 16 + lr) * XSTR + quad * 8];
    const short8 bx1 = *(const short8*)&xs[(w * 16 + lr) * XSTR + 32 + quad * 8];

    // ---- Q: C^T[h][t], store ushort4 (4 consecutive h) to [B,T,H] ----
    {
        const unsigned short* Wrow = Wts;
#pragma unroll
        for (int ht = 0; ht < 8; ++ht) {
            const short8 aw0 = *(const short8*)(Wrow + (ht * 16 + lr) * WSTR + quad * 8);
            const short8 aw1 = *(const short8*)(Wrow + (ht * 16 + lr) * WSTR + 32 + quad * 8);
            floatx4 acc = (floatx4)0.f;
            acc = __builtin_amdgcn_mfma_f32_16x16x32_bf16(aw0, bx0, acc, 0, 0, 0);
            acc = __builtin_amdgcn_mfma_f32_16x16x32_bf16(aw1, bx1, acc, 0, 0, 0);
            ushort4 st = { f2bf(acc[0]), f2bf(acc[1]), f2bf(acc[2]), f2bf(acc[3]) };
            *(ushort4*)(qb + (rbase + w * 16 + lr) * HH + ht * 16 + quad * 4) = st;
        }
    }
    // ---- K: C^T[h][t], store to fragment-tiled Kf ----
    {
        const unsigned short* Wrow = Wts + 1 * HH * WSTR;
        const int khp = w >> 1;
        const int lqp = (w & 1) * 16 + lr;             // t-local & 31
        unsigned short* kdst = Kf + ((long long)((b * 64 + kblk) * 2 + khp)) * 4096
                             + ((quad >> 1) & 1) * 256 + lqp * 8 + (quad & 1) * 4;
#pragma unroll
        for (int ht = 0; ht < 8; ++ht) {               // ht == st (d>>4)
            const short8 aw0 = *(const short8*)(Wrow + (ht * 16 + lr) * WSTR + quad * 8);
            const short8 aw1 = *(const short8*)(Wrow + (ht * 16 + lr) * WSTR + 32 + quad * 8);
            floatx4 acc = (floatx4)0.f;
            acc = __builtin_amdgcn_mfma_f32_16x16x32_bf16(aw0, bx0, acc, 0, 0, 0);
            acc = __builtin_amdgcn_mfma_f32_16x16x32_bf16(aw1, bx1, acc, 0, 0, 0);
            ushort4 st = { f2bf(acc[0]), f2bf(acc[1]), f2bf(acc[2]), f2bf(acc[3]) };
            *(ushort4*)(kdst + ht * 512) = st;
        }
    }
    // ---- V: C[t][h] (lane holds 4 consecutive t at fixed h), store to Vf ----
    {
        const unsigned short* Wrow = Wts + 2 * HH * WSTR;
        const int khv = w >> 1, ksv = w & 1, lsv = (quad >> 1) & 1;
        unsigned short* vdst = Vf + (long long)(b * 64 + kblk) * 8192 + khv * 4096
                             + ksv * 512 + lsv * 256 + (quad & 1) * 4;
#pragma unroll
        for (int htp = 0; htp < 8; ++htp) {
            const short8 bw0 = *(const short8*)(Wrow + (htp * 16 + lr) * WSTR + quad * 8);
            const short8 bw1 = *(const short8*)(Wrow + (htp * 16 + lr) * WSTR + 32 + quad * 8);
            floatx4 acc = (floatx4)0.f;
            acc = __builtin_amdgcn_mfma_f32_16x16x32_bf16(bx0, bw0, acc, 0, 0, 0);
            acc = __builtin_amdgcn_mfma_f32_16x16x32_bf16(bx1, bw1, acc, 0, 0, 0);
            // h = htp*16+lr -> htv = htp>>1, lqv = (htp&1)*16+lr
            ushort4 st = { f2bf(acc[0]), f2bf(acc[1]), f2bf(acc[2]), f2bf(acc[3]) };
            *(ushort4*)(vdst + (htp >> 1) * 1024 + ((htp & 1) * 16 + lr) * 8) = st;
        }
    }
}

// ---------------- Kernel 2: barrier-free flash attention ----------------
// Wave w: kh = w&1 (32-key half), qh = w>>1 (32-query half). No __syncthreads in the loop.
// 32x32x16: A[m=lane&31][k=(lane>>5)*8+j]; B[k][n=lane&31]; C/D: col=lane&31,
// row=(reg&3)+8*(reg>>2)+4*(lane>>5). No-max softmax (scores in log2 domain via Wq).
__global__ __launch_bounds__(NTH, 2) void flash_mfma(
    const unsigned short* __restrict__ qb,
    const unsigned short* __restrict__ Kf,
    const unsigned short* __restrict__ Vf,
    float* __restrict__ out)
{
    __shared__ __align__(16) float ex[2][64 * 68];   // O^T exchange (epilogue only)
    __shared__ float Lx[4][32];

    const int tid  = threadIdx.x;
    const int w    = tid >> 6;
    const int lane = tid & 63;
    const int lq   = lane & 31;
    const int ls   = lane >> 5;
    const int kh   = w & 1;
    const int qh   = w >> 1;

    // balanced CU pairing: ids i and i+256 share a CU; qt pair sums to 63
    const int b = blockIdx.x & 7;
    const int s = blockIdx.x >> 3;
    const int qt = (s < 32) ? (63 - s) : (s - 32);
    const int q0 = qt * 64;
    const long long baset = (long long)b * TT;

    const unsigned short* kptr = Kf + ((long long)(b * 128 + kh)) * 4096 + lane * 8;
    const unsigned short* vptr = Vf + ((long long)b * 64) * 8192 + kh * 4096 + lane * 8;

    // Q fragments: row q0+qh*32+lq, d = st*16 + ls*8 + j
    short8 aq[8];
    {
        const unsigned short* qrp = qb + (baset + q0 + qh * 32 + lq) * HH + ls * 8;
#pragma unroll
        for (int st = 0; st < 8; ++st)
            aq[st] = *(const short8*)(qrp + st * 16);
    }

    floatx16 o_acc[4];   // O^T partial: h = ht*32 + row(reg,ls), q = qh*32+lq
#pragma unroll
    for (int ht = 0; ht < 4; ++ht) o_acc[ht] = (floatx16)0.f;
    float l_lane = 0.f;

    for (int kt = 0; kt <= qt; ++kt) {
        const unsigned short* kp = kptr + (long long)kt * 8192;
        const unsigned short* vp = vptr + (long long)kt * 8192;

        short8 kfr[8], vfr[8];
#pragma unroll
        for (int st = 0; st < 8; ++st)
            kfr[st] = *(const short8*)(kp + st * 512);
#pragma unroll
        for (int i = 0; i < 8; ++i)                    // ht = i>>1, ks = i&1
            vfr[i] = *(const short8*)(vp + (i >> 1) * 1024 + (i & 1) * 512);

        const bool diag = (kt == qt);
        if (diag && kh > qh) continue;                 // wave-tile fully masked

        // ---- S^T = K Q^T : one 32x32 tile per wave ----
        floatx16 s_acc = (floatx16)0.f;
#pragma unroll
        for (int st = 0; st < 8; ++st)
            s_acc = __builtin_amdgcn_mfma_f32_32x32x16_bf16(kfr[st], aq[st], s_acc, 0, 0, 0);

        // ---- p = exp2(s), diag mask, l accumulation ----
        float p[16];
        if (diag && kh == qh) {
#pragma unroll
            for (int reg = 0; reg < 16; ++reg) {
                const int kk = (reg & 3) + 8 * (reg >> 2) + 4 * ls;
                p[reg] = (kk <= lq) ? exp2f(s_acc[reg]) : 0.f;
            }
        } else {
#pragma unroll
            for (int reg = 0; reg < 16; ++reg)
                p[reg] = exp2f(s_acc[reg]);
        }
#pragma unroll
        for (int reg = 0; reg < 16; ++reg) l_lane += p[reg];

        // ---- build P B-frags in-register (C-layout -> B-layout via shfl_xor 32) ----
        unsigned int g[8], pg[8];
#pragma unroll
        for (int i = 0; i < 8; ++i) g[i] = pack2bf(p[2 * i], p[2 * i + 1]);
#pragma unroll
        for (int i = 0; i < 8; ++i) pg[i] = __shfl_xor((int)g[i], 32);
        short8 bp[2];
#pragma unroll
        for (int ks = 0; ks < 2; ++ks) {
            union { short8 s; unsigned int u[4]; } fr;
            const int bs = ks * 4;
            if (ls == 0) {
                fr.u[0] = g[bs];     fr.u[1] = g[bs + 1];
                fr.u[2] = pg[bs];    fr.u[3] = pg[bs + 1];
            } else {
                fr.u[0] = pg[bs + 2]; fr.u[1] = pg[bs + 3];
                fr.u[2] = g[bs + 2];  fr.u[3] = g[bs + 3];
            }
            bp[ks] = fr.s;
        }

        // ---- O^T += V^T P^T ----
#pragma unroll
        for (int ht = 0; ht < 4; ++ht) {
            o_acc[ht] = __builtin_amdgcn_mfma_f32_32x32x16_bf16(vfr[ht * 2 + 0], bp[0], o_acc[ht], 0, 0, 0);
            o_acc[ht] = __builtin_amdgcn_mfma_f32_32x32x16_bf16(vfr[ht * 2 + 1], bp[1], o_acc[ht], 0, 0, 0);
        }
    }

    // ---- epilogue: combine ls then kh halves, divide by l, packed stores ----
    const float l2 = l_lane + __shfl_xor(l_lane, 32);
    if (lane < 32) Lx[w][lq] = l2;
    if (kh == 1) {
        float* e = &ex[qh][lane * 68];
#pragma unroll
        for (int ht = 0; ht < 4; ++ht)
#pragma unroll
            for (int rg = 0; rg < 4; ++rg) {
                float4 v = make_float4(o_acc[ht][rg * 4 + 0], o_acc[ht][rg * 4 + 1],
                                       o_acc[ht][rg * 4 + 2], o_acc[ht][rg * 4 + 3]);
                *(float4*)&e[ht * 16 + rg * 4] = v;
            }
    }
    __syncthreads();
    if (kh == 0) {
        const float linv = 1.f / (Lx[2 * qh][lq] + Lx[2 * qh + 1][lq]);
        const float* e = &ex[qh][lane * 68];
        float* op = out + (baset + q0 + qh * 32 + lq) * HH;
#pragma unroll
        for (int ht = 0; ht < 4; ++ht)
#pragma unroll
            for (int rg = 0; rg < 4; ++rg) {
                const float4 pv = *(const float4*)&e[ht * 16 + rg * 4];
                float4 st = make_float4((o_acc[ht][rg * 4 + 0] + pv.x) * linv,
                                        (o_acc[ht][rg * 4 + 1] + pv.y) * linv,
                                        (o_acc[ht][rg * 4 + 2] + pv.z) * linv,
                                        (o_acc[ht][rg * 4 + 3] + pv.w) * linv);
                *(float4*)(op + ht * 32 + rg * 8 + 4 * ls) = st;
            }
    }
}

extern "C" void kernel_launch(void* const* d_in, const int* in_sizes, int n_in,
                              void* d_out, int out_size, void* d_ws, size_t ws_size,
                              hipStream_t stream)
{
    const float* x  = (const float*)d_in[0];
    const float* Wq = (const float*)d_in[1];
    const float* Wk = (const float*)d_in[2];
    const float* Wv = (const float*)d_in[3];
    float* out = (float*)d_out;

    const long long n = (long long)BB * TT * HH;   // 4,194,304
    unsigned short* qb = (unsigned short*)d_ws;
    unsigned short* Kf = qb + n;
    unsigned short* Vf = Kf + n;

    qkv_mfma<<<BB * (TT / 64), NTH, 0, stream>>>(x, Wq, Wk, Wv, qb, Kf, Vf);
    flash_mfma<<<BB * (TT / 64), NTH, 0, stream>>>(qb, Kf, Vf, out);
}

// Round 7
// 162.778 us; speedup vs baseline: 2.1636x; 1.0840x over previous
//
#include <hip/hip_runtime.h>
#include <math.h>

// nanoGPT Head: x[B,T,C] @ W{q,k,v}[C,H] -> causal softmax(QK^T/sqrt(H)) V
#define BB 8
#define TT 4096
#define CC 64
#define HH 128
#define NTH 256
#define XSTR 72        // proj x stride (bf16)
#define WSTR 72        // proj W stride (bf16)
// 128^-0.5 * log2(e): folded into Wq so S-scores are in log2 domain
#define QSCALE ((float)(0.08838834764831845 * 1.4426950408889634))

typedef __attribute__((ext_vector_type(8)))  short short8;    // 8 bf16 (MFMA A/B frag)
typedef __attribute__((ext_vector_type(4)))  float floatx4;   // 16x16 C/D frag
typedef __attribute__((ext_vector_type(16))) float floatx16;  // 32x32 C/D frag

__device__ __forceinline__ unsigned short f2bf(float f) {
    union { float f; unsigned int u; } un; un.f = f;
    unsigned int r = un.u + 0x7FFF + ((un.u >> 16) & 1);   // RNE
    return (unsigned short)(r >> 16);
}
__device__ __forceinline__ unsigned int pack2bf(float a, float b) {
    return (unsigned int)f2bf(a) | ((unsigned int)f2bf(b) << 16);
}
__device__ __forceinline__ float bflo(unsigned int u) {
    union { unsigned int u; float f; } x; x.u = u << 16; return x.f;
}
__device__ __forceinline__ float bfhi(unsigned int u) {
    union { unsigned int u; float f; } x; x.u = u & 0xffff0000u; return x.f;
}

// ---------------- Kernel 1: QKV projection via MFMA (unchanged from R6) ----------------
// Q -> [B,T,H] row-major bf16.
// K -> fragment-tiled: chunk @ ((b*64+kt)*2+kh)*4096 + st*512 + lane*8 shorts
// V -> fragment-tiled: chunk @ (b*64+kt)*8192 + kh*4096 + ht*1024 + ks*512 + lane*8
__global__ __launch_bounds__(NTH) void qkv_mfma(
    const float* __restrict__ x,
    const float* __restrict__ Wq, const float* __restrict__ Wk, const float* __restrict__ Wv,
    unsigned short* __restrict__ qb, unsigned short* __restrict__ Kf,
    unsigned short* __restrict__ Vf)
{
    __shared__ __align__(16) unsigned short xs[64 * XSTR];
    __shared__ __align__(16) unsigned short Wts[3 * HH * WSTR];

    const int tid  = threadIdx.x;
    const int w    = tid >> 6;
    const int lane = tid & 63;
    const int quad = lane >> 4;
    const int lr   = lane & 15;

    const int b    = blockIdx.x >> 6;
    const int kblk = blockIdx.x & 63;
    const int t0   = kblk * 64;
    const long long rbase = (long long)b * TT + t0;

#pragma unroll
    for (int i = 0; i < 4; ++i) {
        const int idx = tid + i * NTH;
        const int r = idx >> 4, c4 = idx & 15;
        const float4 v = *(const float4*)(x + (rbase + r) * CC + c4 * 4);
        unsigned short tmp[4] = { f2bf(v.x), f2bf(v.y), f2bf(v.z), f2bf(v.w) };
        *(unsigned long long*)&xs[r * XSTR + c4 * 4] = *(unsigned long long*)tmp;
    }
#pragma unroll
    for (int mat = 0; mat < 3; ++mat) {
        const float* W = mat == 0 ? Wq : (mat == 1 ? Wk : Wv);
        const float s = mat == 0 ? QSCALE : 1.0f;
#pragma unroll
        for (int i = 0; i < 32; ++i) {
            const int idx = tid + i * NTH;
            const int c = idx >> 7, h = idx & 127;
            Wts[(mat * HH + h) * WSTR + c] = f2bf(W[idx] * s);
        }
    }
    __syncthreads();

    const short8 bx0 = *(const short8*)&xs[(w * 16 + lr) * XSTR + quad * 8];
    const short8 bx1 = *(const short8*)&xs[(w * 16 + lr) * XSTR + 32 + quad * 8];

    // Q
    {
        const unsigned short* Wrow = Wts;
#pragma unroll
        for (int ht = 0; ht < 8; ++ht) {
            const short8 aw0 = *(const short8*)(Wrow + (ht * 16 + lr) * WSTR + quad * 8);
            const short8 aw1 = *(const short8*)(Wrow + (ht * 16 + lr) * WSTR + 32 + quad * 8);
            floatx4 acc = (floatx4)0.f;
            acc = __builtin_amdgcn_mfma_f32_16x16x32_bf16(aw0, bx0, acc, 0, 0, 0);
            acc = __builtin_amdgcn_mfma_f32_16x16x32_bf16(aw1, bx1, acc, 0, 0, 0);
            ushort4 st = { f2bf(acc[0]), f2bf(acc[1]), f2bf(acc[2]), f2bf(acc[3]) };
            *(ushort4*)(qb + (rbase + w * 16 + lr) * HH + ht * 16 + quad * 4) = st;
        }
    }
    // K fragment-tiled
    {
        const unsigned short* Wrow = Wts + 1 * HH * WSTR;
        const int khp = w >> 1;
        const int lqp = (w & 1) * 16 + lr;
        unsigned short* kdst = Kf + ((long long)((b * 64 + kblk) * 2 + khp)) * 4096
                             + ((quad >> 1) & 1) * 256 + lqp * 8 + (quad & 1) * 4;
#pragma unroll
        for (int ht = 0; ht < 8; ++ht) {
            const short8 aw0 = *(const short8*)(Wrow + (ht * 16 + lr) * WSTR + quad * 8);
            const short8 aw1 = *(const short8*)(Wrow + (ht * 16 + lr) * WSTR + 32 + quad * 8);
            floatx4 acc = (floatx4)0.f;
            acc = __builtin_amdgcn_mfma_f32_16x16x32_bf16(aw0, bx0, acc, 0, 0, 0);
            acc = __builtin_amdgcn_mfma_f32_16x16x32_bf16(aw1, bx1, acc, 0, 0, 0);
            ushort4 st = { f2bf(acc[0]), f2bf(acc[1]), f2bf(acc[2]), f2bf(acc[3]) };
            *(ushort4*)(kdst + ht * 512) = st;
        }
    }
    // V fragment-tiled
    {
        const unsigned short* Wrow = Wts + 2 * HH * WSTR;
        const int khv = w >> 1, ksv = w & 1, lsv = (quad >> 1) & 1;
        unsigned short* vdst = Vf + (long long)(b * 64 + kblk) * 8192 + khv * 4096
                             + ksv * 512 + lsv * 256 + (quad & 1) * 4;
#pragma unroll
        for (int htp = 0; htp < 8; ++htp) {
            const short8 bw0 = *(const short8*)(Wrow + (htp * 16 + lr) * WSTR + quad * 8);
            const short8 bw1 = *(const short8*)(Wrow + (htp * 16 + lr) * WSTR + 32 + quad * 8);
            floatx4 acc = (floatx4)0.f;
            acc = __builtin_amdgcn_mfma_f32_16x16x32_bf16(bx0, bw0, acc, 0, 0, 0);
            acc = __builtin_amdgcn_mfma_f32_16x16x32_bf16(bx1, bw1, acc, 0, 0, 0);
            ushort4 st = { f2bf(acc[0]), f2bf(acc[1]), f2bf(acc[2]), f2bf(acc[3]) };
            *(ushort4*)(vdst + (htp >> 1) * 1024 + ((htp & 1) * 16 + lr) * 8) = st;
        }
    }
}

// ---------------- Kernel 2: split-K flash (partials are LINEAR in no-max softmax) ----------------
// Block = (qt, b, chunk c of 4). len = ceil((qt+1)/4); tiles [c*len, min(qt, c*len+len-1)].
// Writes unnormalized partial O (bf16 [64q][128h]) + l (fp32 [64q]) per (b,qt,c).
__global__ __launch_bounds__(NTH, 2) void flash_splitk(
    const unsigned short* __restrict__ qb,
    const unsigned short* __restrict__ Kf,
    const unsigned short* __restrict__ Vf,
    unsigned short* __restrict__ Ob, float* __restrict__ Lb)
{
    __shared__ __align__(16) float ex[2][64 * 68];
    __shared__ float Lx[4][32];

    const int tid  = threadIdx.x;
    const int w    = tid >> 6;
    const int lane = tid & 63;
    const int lq   = lane & 31;
    const int ls   = lane >> 5;
    const int kh   = w & 1;
    const int qh   = w >> 1;

    const int id  = blockIdx.x;
    const int qt  = 63 - (id >> 5);        // heavy chunks dispatched first
    const int b   = (id >> 2) & 7;
    const int c   = id & 3;
    const int len = (qt + 4) >> 2;
    const int lo  = c * len;
    if (lo > qt) return;                   // empty chunk
    const int hi  = (lo + len - 1 < qt) ? (lo + len - 1) : qt;

    const int q0 = qt * 64;
    const long long baset = (long long)b * TT;

    const unsigned short* kptr = Kf + ((long long)(b * 128 + kh)) * 4096 + lane * 8;
    const unsigned short* vptr = Vf + ((long long)b * 64) * 8192 + kh * 4096 + lane * 8;

    // Q fragments: row q0+qh*32+lq, d = st*16 + ls*8 + j
    short8 aq[8];
    {
        const unsigned short* qrp = qb + (baset + q0 + qh * 32 + lq) * HH + ls * 8;
#pragma unroll
        for (int st = 0; st < 8; ++st)
            aq[st] = *(const short8*)(qrp + st * 16);
    }

    floatx16 o_acc[4];
#pragma unroll
    for (int ht = 0; ht < 4; ++ht) o_acc[ht] = (floatx16)0.f;
    float l_lane = 0.f;

    for (int kt = lo; kt <= hi; ++kt) {
        const unsigned short* kp = kptr + (long long)kt * 8192;
        const unsigned short* vp = vptr + (long long)kt * 8192;

        short8 kfr[8], vfr[8];
#pragma unroll
        for (int st = 0; st < 8; ++st)
            kfr[st] = *(const short8*)(kp + st * 512);
#pragma unroll
        for (int i = 0; i < 8; ++i)
            vfr[i] = *(const short8*)(vp + (i >> 1) * 1024 + (i & 1) * 512);

        const bool diag = (kt == qt);
        if (diag && kh > qh) continue;     // wave-tile fully masked

        // S^T = K Q^T
        floatx16 s_acc = (floatx16)0.f;
#pragma unroll
        for (int st = 0; st < 8; ++st)
            s_acc = __builtin_amdgcn_mfma_f32_32x32x16_bf16(kfr[st], aq[st], s_acc, 0, 0, 0);

        // p = exp2(s), diag mask, l accumulation
        float p[16];
        if (diag && kh == qh) {
#pragma unroll
            for (int reg = 0; reg < 16; ++reg) {
                const int kk = (reg & 3) + 8 * (reg >> 2) + 4 * ls;
                p[reg] = (kk <= lq) ? exp2f(s_acc[reg]) : 0.f;
            }
        } else {
#pragma unroll
            for (int reg = 0; reg < 16; ++reg)
                p[reg] = exp2f(s_acc[reg]);
        }
#pragma unroll
        for (int reg = 0; reg < 16; ++reg) l_lane += p[reg];

        // P C-layout -> B-layout in-register
        unsigned int g[8], pg[8];
#pragma unroll
        for (int i = 0; i < 8; ++i) g[i] = pack2bf(p[2 * i], p[2 * i + 1]);
#pragma unroll
        for (int i = 0; i < 8; ++i) pg[i] = __shfl_xor((int)g[i], 32);
        short8 bp[2];
#pragma unroll
        for (int ks = 0; ks < 2; ++ks) {
            union { short8 s; unsigned int u[4]; } fr;
            const int bs = ks * 4;
            if (ls == 0) {
                fr.u[0] = g[bs];      fr.u[1] = g[bs + 1];
                fr.u[2] = pg[bs];     fr.u[3] = pg[bs + 1];
            } else {
                fr.u[0] = pg[bs + 2]; fr.u[1] = pg[bs + 3];
                fr.u[2] = g[bs + 2];  fr.u[3] = g[bs + 3];
            }
            bp[ks] = fr.s;
        }

        // O^T += V^T P^T
#pragma unroll
        for (int ht = 0; ht < 4; ++ht) {
            o_acc[ht] = __builtin_amdgcn_mfma_f32_32x32x16_bf16(vfr[ht * 2 + 0], bp[0], o_acc[ht], 0, 0, 0);
            o_acc[ht] = __builtin_amdgcn_mfma_f32_32x32x16_bf16(vfr[ht * 2 + 1], bp[1], o_acc[ht], 0, 0, 0);
        }
    }

    // epilogue: combine ls then kh halves; write unnormalized partial (bf16) + l (fp32)
    const float l2 = l_lane + __shfl_xor(l_lane, 32);
    if (lane < 32) Lx[w][lq] = l2;
    if (kh == 1) {
        float* e = &ex[qh][lane * 68];
#pragma unroll
        for (int ht = 0; ht < 4; ++ht)
#pragma unroll
            for (int rg = 0; rg < 4; ++rg) {
                float4 v = make_float4(o_acc[ht][rg * 4 + 0], o_acc[ht][rg * 4 + 1],
                                       o_acc[ht][rg * 4 + 2], o_acc[ht][rg * 4 + 3]);
                *(float4*)&e[ht * 16 + rg * 4] = v;
            }
    }
    __syncthreads();
    if (kh == 0) {
        const int pid = ((b * 64 + qt) << 2) + c;
        Lb[pid * 64 + qh * 32 + lq] = Lx[2 * qh][lq] + Lx[2 * qh + 1][lq];
        const float* e = &ex[qh][lane * 68];
        unsigned short* od = Ob + (long long)pid * 8192 + (qh * 32 + lq) * HH;
#pragma unroll
        for (int ht = 0; ht < 4; ++ht)
#pragma unroll
            for (int rg = 0; rg < 4; ++rg) {
                const float4 pv = *(const float4*)&e[ht * 16 + rg * 4];
                ushort4 st = { f2bf(o_acc[ht][rg * 4 + 0] + pv.x),
                               f2bf(o_acc[ht][rg * 4 + 1] + pv.y),
                               f2bf(o_acc[ht][rg * 4 + 2] + pv.z),
                               f2bf(o_acc[ht][rg * 4 + 3] + pv.w) };
                *(ushort4*)(od + ht * 32 + rg * 8 + 4 * ls) = st;
            }
    }
}

// ---------------- Kernel 3: combine partials, divide by l ----------------
// Block = (b,qt); thread t: q = t>>2, h-group (t&3)*32. Sums <=4 partials, writes out fp32.
__global__ __launch_bounds__(NTH) void combine(
    const unsigned short* __restrict__ Ob, const float* __restrict__ Lb,
    float* __restrict__ out)
{
    const int id = blockIdx.x;
    const int b = id & 7, qt = id >> 3;
    const int len = (qt + 4) >> 2;
    const int tid = threadIdx.x;
    const int q = tid >> 2;
    const int hg = tid & 3;
    const int pid0 = (b * 64 + qt) << 2;

    float acc[32];
#pragma unroll
    for (int i = 0; i < 32; ++i) acc[i] = 0.f;
    float ltot = 0.f;

#pragma unroll
    for (int c = 0; c < 4; ++c) {
        if (c * len > qt) break;
        ltot += Lb[(pid0 + c) * 64 + q];
        const uint4* src = (const uint4*)(Ob + (long long)(pid0 + c) * 8192 + q * HH + hg * 32);
#pragma unroll
        for (int g = 0; g < 4; ++g) {
            const uint4 d = src[g];
            acc[g * 8 + 0] += bflo(d.x); acc[g * 8 + 1] += bfhi(d.x);
            acc[g * 8 + 2] += bflo(d.y); acc[g * 8 + 3] += bfhi(d.y);
            acc[g * 8 + 4] += bflo(d.z); acc[g * 8 + 5] += bfhi(d.z);
            acc[g * 8 + 6] += bflo(d.w); acc[g * 8 + 7] += bfhi(d.w);
        }
    }
    const float inv = 1.f / ltot;
    float* op = out + ((long long)b * TT + qt * 64 + q) * HH + hg * 32;
#pragma unroll
    for (int g = 0; g < 8; ++g) {
        float4 st = make_float4(acc[g * 4 + 0] * inv, acc[g * 4 + 1] * inv,
                                acc[g * 4 + 2] * inv, acc[g * 4 + 3] * inv);
        *(float4*)(op + g * 4) = st;
    }
}

extern "C" void kernel_launch(void* const* d_in, const int* in_sizes, int n_in,
                              void* d_out, int out_size, void* d_ws, size_t ws_size,
                              hipStream_t stream)
{
    const float* x  = (const float*)d_in[0];
    const float* Wq = (const float*)d_in[1];
    const float* Wk = (const float*)d_in[2];
    const float* Wv = (const float*)d_in[3];
    float* out = (float*)d_out;

    const long long n = (long long)BB * TT * HH;   // 4,194,304
    unsigned short* qb = (unsigned short*)d_ws;
    unsigned short* Kf = qb + n;
    unsigned short* Vf = Kf + n;
    unsigned short* Ob = Vf + n;                   // 2048 * 8192 bf16 = 33.5 MB
    float*          Lb = (float*)(Ob + (long long)2048 * 8192);  // 2048*64 fp32

    qkv_mfma<<<BB * (TT / 64), NTH, 0, stream>>>(x, Wq, Wk, Wv, qb, Kf, Vf);
    flash_splitk<<<2048, NTH, 0, stream>>>(qb, Kf, Vf, Ob, Lb);
    combine<<<BB * 64, NTH, 0, stream>>>(Ob, Lb, out);
}